// Round 5
// baseline (357.770 us; speedup 1.0000x reference)
//
#include <hip/hip_runtime.h>
#include <math.h>

#define N_NODES 100000
#define N_PART  5000
#define N_EDGES 1000000
#define D_NODE  128
#define D_PART  128
#define D_ATT   20
#define CAP     384   // bucket capacity (max degree ~260 for Binomial(1M,1/5000))
#define TPV3    10    // particles per block in gru_fused_v4 (5000 = 500*10)

__device__ __forceinline__ float sigmoid_(float x) { return 1.f / (1.f + __expf(-x)); }
__device__ __forceinline__ float tanh_(float x)    { return 1.f - 2.f / (__expf(2.f * x) + 1.f); }

// ---------------------------------------------------------------------------
// P0a: Wbig rows 0..127 (dot part):
//   Wbig[k][j] = sum_m valW[k][m]*Wih[j][m]   for j<384; 0 for j>=384
// LDS-tiled: 32 k-rows x 64 j-rows per block, grid 4x6 = 24 blocks.
// ---------------------------------------------------------------------------
__global__ __launch_bounds__(256) void build_wbig_dot_kernel(
    const float* __restrict__ valW, const float* __restrict__ Wih,
    float* __restrict__ Wbig)
{
    __shared__ float s_a[32][128];   // valW rows
    __shared__ float s_b[64][128];   // Wih rows
    int kt = blockIdx.x / 6, jt = blockIdx.x % 6;
    int k0 = kt * 32, j0 = jt * 64;
    int t = threadIdx.x;

    for (int f = t; f < 32 * 32; f += 256) {       // 32 rows x 32 quads
        int r = f >> 5, c4 = (f & 31) * 4;
        *(float4*)&s_a[r][c4] = *(const float4*)(valW + (size_t)(k0 + r) * 128 + c4);
    }
    for (int f = t; f < 64 * 32; f += 256) {
        int r = f >> 5, c4 = (f & 31) * 4;
        *(float4*)&s_b[r][c4] = *(const float4*)(Wih + (size_t)(j0 + r) * 128 + c4);
    }
    __syncthreads();

    #pragma unroll
    for (int f = 0; f < 8; f++) {
        int idx = t + f * 256;        // 2048 outputs
        int kk = idx >> 6, jj = idx & 63;
        float acc = 0.f;
        #pragma unroll 8
        for (int m = 0; m < 128; m++) acc += s_a[kk][m] * s_b[jj][m];
        Wbig[(size_t)(k0 + kk) * 512 + j0 + jj] = acc;
    }
    // zero-fill j in [384,512) for these k rows (blocks with jt==0 do it)
    if (jt == 0) {
        for (int f = t; f < 32 * 128; f += 256) {
            int kk = f >> 7, jj = 384 + (f & 127);
            Wbig[(size_t)(k0 + kk) * 512 + jj] = 0.f;
        }
    }
}

// P0b: Wbig rows 128..255 (copy part):
//   j<256: Whh[j][kp]; 256<=j<384: 0; j>=384: Whh[j-128][kp]
__global__ __launch_bounds__(256) void build_wbig_copy_kernel(
    const float* __restrict__ Whh, float* __restrict__ Wbig)
{
    int idx = blockIdx.x * 256 + threadIdx.x;   // 65536
    int kp = idx >> 9;
    int j = idx & 511;
    float v = 0.f;
    if (j < 256)       v = Whh[j * 128 + kp];
    else if (j >= 384) v = Whh[(j - 128) * 128 + kp];
    Wbig[(size_t)(128 + kp) * 512 + j] = v;
}

// P0c: bvec[c] = sum_m valb[m] * Wih[c][m],  c < 384
__global__ __launch_bounds__(256) void build_bvec_kernel(
    const float* __restrict__ valb, const float* __restrict__ Wih,
    float* __restrict__ bvec)
{
    int c = blockIdx.x * 256 + threadIdx.x;
    if (c < 384) {
        float acc = 0.f;
        #pragma unroll 8
        for (int m = 0; m < 128; m++) acc += valb[m] * Wih[c * 128 + m];
        bvec[c] = acc;
    }
}

// ---------------------------------------------------------------------------
// K1 v2: 32 particles/block. query = [ph|gr]@qW + qb; fold keyW/keyb:
//   qk[p][j] = sum_a keyW[j][a]*query[p][a];  qoff[p] = keyb . query[p]
// ---------------------------------------------------------------------------
__global__ __launch_bounds__(256) void query_qk_v2(
    const float* __restrict__ ph, const float* __restrict__ gr,
    const float* __restrict__ qW, const float* __restrict__ qb,
    const float* __restrict__ keyW, const float* __restrict__ keyb,
    float* __restrict__ qk, float* __restrict__ qoff)
{
    __shared__ float s_in[32][256];    // 32 KB
    __shared__ float s_qW[256 * 20];   // 20 KB
    __shared__ float s_kWT[20][128];   // keyW transposed, 10 KB
    __shared__ float s_q[32][20];

    int t = threadIdx.x;
    int pbase = blockIdx.x * 32;

    for (int f = t; f < 32 * 64; f += 256) {
        int pl = f >> 6, c4 = (f & 63) * 4;
        int p = min(pbase + pl, N_PART - 1);
        float4 v;
        if (c4 < 128) v = *(const float4*)(ph + (size_t)p * 128 + c4);
        else          v = *(const float4*)(gr + (size_t)p * 128 + (c4 - 128));
        *(float4*)&s_in[pl][c4] = v;
    }
    for (int f = t; f < 1280; f += 256)
        *(float4*)&s_qW[f * 4] = *(const float4*)(qW + f * 4);
    for (int f = t; f < 2560; f += 256) {
        int j = f / 20, a = f % 20;
        s_kWT[a][j] = keyW[f];
    }
    __syncthreads();

    // phase 1: query (32 x 20)
    for (int idx = t; idx < 32 * 20; idx += 256) {
        int pl = idx / 20, a = idx % 20;
        float acc = qb[a];
        #pragma unroll 8
        for (int k = 0; k < 256; k++) acc += s_in[pl][k] * s_qW[k * 20 + a];
        s_q[pl][a] = acc;
    }
    __syncthreads();

    // phase 2: qk (32 x 128) + qoff
    for (int idx = t; idx < 32 * 128; idx += 256) {
        int pl = idx >> 7, j = idx & 127;
        int p = pbase + pl;
        if (p < N_PART) {
            float acc = 0.f;
            #pragma unroll
            for (int a = 0; a < D_ATT; a++) acc += s_kWT[a][j] * s_q[pl][a];
            qk[(size_t)p * 128 + j] = acc;
        }
    }
    if (t < 32) {
        int p = pbase + t;
        if (p < N_PART) {
            float o = 0.f;
            #pragma unroll
            for (int a = 0; a < D_ATT; a++) o += keyb[a] * s_q[t][a];
            qoff[p] = o;
        }
    }
}

// ---------------------------------------------------------------------------
// K2: single-pass bucketing (unstable order is fine — we only sum).
// ---------------------------------------------------------------------------
__global__ __launch_bounds__(256) void bucket_scatter_kernel(
    const int* __restrict__ src, const int* __restrict__ dst,
    int* __restrict__ cnt, int* __restrict__ ssrc)
{
    int stride = gridDim.x * 256;
    for (int e = blockIdx.x * 256 + threadIdx.x; e < N_EDGES; e += stride) {
        int d = dst[e];
        int pos = atomicAdd(&cnt[d], 1);
        if (pos < CAP) ssrc[(size_t)d * CAP + pos] = src[e];
    }
}

// ---------------------------------------------------------------------------
// K3: per-dst edge accumulation. Half-wave (32 lanes x float4) per edge,
// 4 pairs (8 edges) in flight per wave per iteration.
// ---------------------------------------------------------------------------
__global__ __launch_bounds__(256) void edge_agg_kernel(
    const float* __restrict__ nodes, const float* __restrict__ qk,
    const float* __restrict__ qoff, const int* __restrict__ cnt,
    const int* __restrict__ ssrc,
    float* __restrict__ agg, float* __restrict__ att_sum)
{
    const float norm = 0.22360679774997896f;  // 1/sqrt(20)
    int p = blockIdx.x;
    int tid = threadIdx.x;
    int lane = tid & 63;
    int wave = tid >> 6;
    int half = lane >> 5;
    int colq = (lane & 31) * 4;

    const float4 q = *(const float4*)(qk + (size_t)p * 128 + colq);
    float qo = qoff[p];
    int beg = p * CAP;
    int n = min(cnt[p], CAP);
    int end = beg + n;
    int np = (n + 1) >> 1;
    int npfull = n >> 1;

    float4 a = {0.f, 0.f, 0.f, 0.f};
    float asum = 0.f;

    int pi = wave;
    for (; pi + 12 < npfull; pi += 16) {
        int e0 = beg + 2 * pi + half;
        int s0 = ssrc[e0];
        int s1 = ssrc[e0 + 8];
        int s2 = ssrc[e0 + 16];
        int s3 = ssrc[e0 + 24];
        float4 x0 = *(const float4*)(nodes + (size_t)s0 * 128 + colq);
        float4 x1 = *(const float4*)(nodes + (size_t)s1 * 128 + colq);
        float4 x2 = *(const float4*)(nodes + (size_t)s2 * 128 + colq);
        float4 x3 = *(const float4*)(nodes + (size_t)s3 * 128 + colq);
        float d0 = x0.x * q.x + x0.y * q.y + x0.z * q.z + x0.w * q.w;
        float d1 = x1.x * q.x + x1.y * q.y + x1.z * q.z + x1.w * q.w;
        float d2 = x2.x * q.x + x2.y * q.y + x2.z * q.z + x2.w * q.w;
        float d3 = x3.x * q.x + x3.y * q.y + x3.z * q.z + x3.w * q.w;
        #pragma unroll
        for (int off = 1; off <= 16; off <<= 1) {
            d0 += __shfl_xor(d0, off, 64);
            d1 += __shfl_xor(d1, off, 64);
            d2 += __shfl_xor(d2, off, 64);
            d3 += __shfl_xor(d3, off, 64);
        }
        float t0 = (d0 + qo) * norm;
        float t1 = (d1 + qo) * norm;
        float t2 = (d2 + qo) * norm;
        float t3 = (d3 + qo) * norm;
        a.x += t0 * x0.x + t1 * x1.x + t2 * x2.x + t3 * x3.x;
        a.y += t0 * x0.y + t1 * x1.y + t2 * x2.y + t3 * x3.y;
        a.z += t0 * x0.z + t1 * x1.z + t2 * x2.z + t3 * x3.z;
        a.w += t0 * x0.w + t1 * x1.w + t2 * x2.w + t3 * x3.w;
        asum += t0 + t1 + t2 + t3;
    }
    for (; pi < np; pi += 4) {
        int e0 = beg + 2 * pi;
        bool has1 = (e0 + 1 < end);
        int s0 = ssrc[e0];
        int s1 = has1 ? ssrc[e0 + 1] : s0;
        int s = half ? s1 : s0;
        float4 x = *(const float4*)(nodes + (size_t)s * 128 + colq);
        float d = x.x * q.x + x.y * q.y + x.z * q.z + x.w * q.w;
        #pragma unroll
        for (int off = 1; off <= 16; off <<= 1) d += __shfl_xor(d, off, 64);
        float att = (d + qo) * norm;
        if (half && !has1) att = 0.f;
        a.x += att * x.x; a.y += att * x.y; a.z += att * x.z; a.w += att * x.w;
        asum += att;
    }

    a.x += __shfl_xor(a.x, 32, 64);
    a.y += __shfl_xor(a.y, 32, 64);
    a.z += __shfl_xor(a.z, 32, 64);
    a.w += __shfl_xor(a.w, 32, 64);
    asum += __shfl_xor(asum, 32, 64);

    __shared__ float s_acc[4][128];
    __shared__ float s_as[4];
    if (lane < 32) {
        *(float4*)&s_acc[wave][colq] = a;
        if (lane == 0) s_as[wave] = asum;
    }
    __syncthreads();

    if (tid < 128) {
        float v = s_acc[0][tid] + s_acc[1][tid] + s_acc[2][tid] + s_acc[3][tid];
        agg[(size_t)p * 128 + tid] = v;
        if (tid == 0) att_sum[p] = s_as[0] + s_as[1] + s_as[2] + s_as[3];
    }
}

// ---------------------------------------------------------------------------
// K4 v4: single K=256 GEMM G=[agg|h]@Wbig (+bias/asum*bvec) + gates+LN+MLP.
// No LDS weight staging: direct coalesced Wbig reads (L2-resident), no
// K-loop barriers. 256 threads, 10 particles/block, 500 blocks.
// ---------------------------------------------------------------------------
__global__ __launch_bounds__(256) void gru_fused_v4(
    const float* __restrict__ agg, const float* __restrict__ att_sum,
    const float* __restrict__ ph,
    const float* __restrict__ Wbig, const float* __restrict__ bvec,
    const float* __restrict__ bih, const float* __restrict__ bhh,
    const float* __restrict__ lng, const float* __restrict__ lnb,
    const float* __restrict__ W1, const float* __restrict__ b1,
    const float* __restrict__ W2, const float* __restrict__ b2,
    float* __restrict__ out)
{
    __shared__ float s_in[TPV3][256];    // [agg | h]
    __shared__ float s_acc[TPV3][512];
    __shared__ float s_ln[TPV3][128];
    __shared__ float s_hid[TPV3][64];

    int t = threadIdx.x;
    int pbase = blockIdx.x * TPV3;

    for (int f = t; f < TPV3 * 64; f += 256) {
        int pl = f >> 6, c4 = (f & 63) * 4;
        int p = pbase + pl;
        float4 v;
        if (c4 < 128) v = *(const float4*)(agg + (size_t)p * 128 + c4);
        else          v = *(const float4*)(ph + (size_t)p * 128 + (c4 - 128));
        *(float4*)&s_in[pl][c4] = v;
    }

    int jq = t & 127;
    int j4 = jq * 4;
    int pg = t >> 7;
    float4 cb, bv;
    if (j4 < 256) {
        float4 bi = *(const float4*)(bih + j4);
        float4 bh = *(const float4*)(bhh + j4);
        cb.x = bi.x + bh.x; cb.y = bi.y + bh.y; cb.z = bi.z + bh.z; cb.w = bi.w + bh.w;
        bv = *(const float4*)(bvec + j4);
    } else if (j4 < 384) {
        cb = *(const float4*)(bih + j4);
        bv = *(const float4*)(bvec + j4);
    } else {
        cb = *(const float4*)(bhh + (j4 - 128));
        bv.x = bv.y = bv.z = bv.w = 0.f;
    }
    float4 acc[5];
    #pragma unroll
    for (int i = 0; i < 5; i++) {
        float as = att_sum[pbase + pg * 5 + i];
        acc[i].x = cb.x + as * bv.x;
        acc[i].y = cb.y + as * bv.y;
        acc[i].z = cb.z + as * bv.z;
        acc[i].w = cb.w + as * bv.w;
    }
    __syncthreads();

    // K-loop: direct global weight reads, no barriers
    #pragma unroll 4
    for (int k = 0; k < 256; k++) {
        float4 w = *(const float4*)(Wbig + (size_t)k * 512 + j4);
        #pragma unroll
        for (int i = 0; i < 5; i++) {
            float x = s_in[pg * 5 + i][k];
            acc[i].x += x * w.x; acc[i].y += x * w.y;
            acc[i].z += x * w.z; acc[i].w += x * w.w;
        }
    }

    #pragma unroll
    for (int i = 0; i < 5; i++)
        *(float4*)&s_acc[pg * 5 + i][j4] = acc[i];
    __syncthreads();

    // gates
    for (int idx = t; idx < TPV3 * 32; idx += 256) {
        int pl = idx >> 5, q = idx & 31;
        int c4 = q * 4;
        float4 r4 = *(const float4*)&s_acc[pl][c4];
        float4 z4 = *(const float4*)&s_acc[pl][128 + c4];
        float4 i4 = *(const float4*)&s_acc[pl][256 + c4];
        float4 n4 = *(const float4*)&s_acc[pl][384 + c4];
        float4 h4 = *(const float4*)&s_in[pl][128 + c4];
        float r0 = sigmoid_(r4.x), r1 = sigmoid_(r4.y), r2 = sigmoid_(r4.z), r3 = sigmoid_(r4.w);
        float z0 = sigmoid_(z4.x), z1 = sigmoid_(z4.y), z2 = sigmoid_(z4.z), z3 = sigmoid_(z4.w);
        float n0 = tanh_(i4.x + r0 * n4.x), n1 = tanh_(i4.y + r1 * n4.y);
        float n2 = tanh_(i4.z + r2 * n4.z), n3 = tanh_(i4.w + r3 * n4.w);
        float4 hn;
        hn.x = (1.f - z0) * n0 + z0 * h4.x;
        hn.y = (1.f - z1) * n1 + z1 * h4.y;
        hn.z = (1.f - z2) * n2 + z2 * h4.z;
        hn.w = (1.f - z3) * n3 + z3 * h4.w;
        *(float4*)&s_ln[pl][c4] = hn;
    }
    __syncthreads();

    // LayerNorm
    {
        int wv = t >> 6, l = t & 63;
        for (int pl = wv; pl < TPV3; pl += 4) {
            float v0 = s_ln[pl][l * 2], v1 = s_ln[pl][l * 2 + 1];
            float sum = v0 + v1, sq = v0 * v0 + v1 * v1;
            #pragma unroll
            for (int off = 1; off <= 32; off <<= 1) {
                sum += __shfl_xor(sum, off, 64);
                sq  += __shfl_xor(sq, off, 64);
            }
            float mu = sum * (1.f / 128.f);
            float var = sq * (1.f / 128.f) - mu * mu;
            float rstd = rsqrtf(var + 1e-5f);
            s_ln[pl][l * 2]     = (v0 - mu) * rstd * lng[l * 2] + lnb[l * 2];
            s_ln[pl][l * 2 + 1] = (v1 - mu) * rstd * lng[l * 2 + 1] + lnb[l * 2 + 1];
        }
    }
    __syncthreads();

    // MLP hidden
    for (int idx = t; idx < TPV3 * 64; idx += 256) {
        int pl = idx >> 6, u = idx & 63;
        float a0 = b1[u];
        #pragma unroll 4
        for (int k = 0; k < 128; k++) a0 += s_ln[pl][k] * W1[k * 64 + u];
        s_hid[pl][u] = fmaxf(a0, 0.f);
    }
    __syncthreads();

    // MLP out + residual
    for (int idx = t; idx < TPV3 * 32; idx += 256) {
        int pl = idx >> 5, q = idx & 31;
        int c4 = q * 4;
        float4 o = *(const float4*)(b2 + c4);
        #pragma unroll 4
        for (int u = 0; u < 64; u++) {
            float av = s_hid[pl][u];
            float4 w = *(const float4*)(W2 + u * 128 + c4);
            o.x += av * w.x; o.y += av * w.y; o.z += av * w.z; o.w += av * w.w;
        }
        float4 h4 = *(const float4*)&s_in[pl][128 + c4];
        float4 res;
        res.x = h4.x + o.x; res.y = h4.y + o.y;
        res.z = h4.z + o.z; res.w = h4.w + o.w;
        *(float4*)(out + (size_t)(pbase + pl) * 128 + c4) = res;
    }
}

// ---------------------------------------------------------------------------
extern "C" void kernel_launch(void* const* d_in, const int* in_sizes, int n_in,
                              void* d_out, int out_size, void* d_ws, size_t ws_size,
                              hipStream_t stream) {
    const float* nodes = (const float*)d_in[0];
    const float* ph    = (const float*)d_in[1];
    const float* gr    = (const float*)d_in[2];
    const int*   src   = (const int*)d_in[3];
    const int*   dst   = (const int*)d_in[4];
    const float* keyW  = (const float*)d_in[5];
    const float* keyb  = (const float*)d_in[6];
    const float* valW  = (const float*)d_in[7];
    const float* valb  = (const float*)d_in[8];
    const float* qW    = (const float*)d_in[9];
    const float* qb    = (const float*)d_in[10];
    const float* Wih   = (const float*)d_in[11];
    const float* Whh   = (const float*)d_in[12];
    const float* bih   = (const float*)d_in[13];
    const float* bhh   = (const float*)d_in[14];
    const float* lng   = (const float*)d_in[15];
    const float* lnb   = (const float*)d_in[16];
    const float* W1    = (const float*)d_in[17];
    const float* b1    = (const float*)d_in[18];
    const float* W2    = (const float*)d_in[19];
    const float* b2    = (const float*)d_in[20];
    float* out = (float*)d_out;

    // workspace layout
    float* ws_f    = (float*)d_ws;
    float* qk      = ws_f;                      // 640,000
    float* qoff    = qk + 640000;               // 5,008
    float* agg     = qoff + 5008;               // 640,000
    float* att_sum = agg + 640000;              // 5,008
    float* Wbig    = att_sum + 5008;            // 131,072
    float* bvec    = Wbig + 131072;             // 512
    int*   cnt     = (int*)(bvec + 512);        // 5,008
    int*   ssrc    = cnt + 5008;                // 5000*384 = 1,920,000

    hipMemsetAsync(cnt, 0, N_PART * sizeof(int), stream);

    build_wbig_dot_kernel<<<24, 256, 0, stream>>>(valW, Wih, Wbig);
    build_wbig_copy_kernel<<<256, 256, 0, stream>>>(Whh, Wbig);
    build_bvec_kernel<<<2, 256, 0, stream>>>(valb, Wih, bvec);
    query_qk_v2<<<(N_PART + 31) / 32, 256, 0, stream>>>(ph, gr, qW, qb, keyW, keyb, qk, qoff);
    bucket_scatter_kernel<<<2048, 256, 0, stream>>>(src, dst, cnt, ssrc);
    edge_agg_kernel<<<N_PART, 256, 0, stream>>>(nodes, qk, qoff, cnt, ssrc, agg, att_sum);
    gru_fused_v4<<<N_PART / TPV3, 256, 0, stream>>>(
        agg, att_sum, ph, Wbig, bvec, bih, bhh, lng, lnb, W1, b1, W2, b2, out);
}

// Round 6
// 326.456 us; speedup vs baseline: 1.0959x; 1.0959x over previous
//
#include <hip/hip_runtime.h>
#include <hip/hip_fp16.h>
#include <math.h>

#define N_NODES 100000
#define N_PART  5000
#define N_EDGES 1000000
#define D_NODE  128
#define D_PART  128
#define D_ATT   20
#define NBLK    128   // counting-sort blocks
#define EPB     ((N_EDGES + NBLK - 1) / NBLK)
#define TPV3    10    // particles per block in gru_fused_v4 (5000 = 500*10)

__device__ __forceinline__ float sigmoid_(float x) { return 1.f / (1.f + __expf(-x)); }
__device__ __forceinline__ float tanh_(float x)    { return 1.f - 2.f / (__expf(2.f * x) + 1.f); }

// ---------------------------------------------------------------------------
// P0a: Wbig rows 0..127: Wbig[k][j] = sum_m valW[k][m]*Wih[j][m] (j<384)
// ---------------------------------------------------------------------------
__global__ __launch_bounds__(256) void build_wbig_dot_kernel(
    const float* __restrict__ valW, const float* __restrict__ Wih,
    float* __restrict__ Wbig)
{
    __shared__ float s_a[32][128];
    __shared__ float s_b[64][128];
    int kt = blockIdx.x / 6, jt = blockIdx.x % 6;
    int k0 = kt * 32, j0 = jt * 64;
    int t = threadIdx.x;

    for (int f = t; f < 32 * 32; f += 256) {
        int r = f >> 5, c4 = (f & 31) * 4;
        *(float4*)&s_a[r][c4] = *(const float4*)(valW + (size_t)(k0 + r) * 128 + c4);
    }
    for (int f = t; f < 64 * 32; f += 256) {
        int r = f >> 5, c4 = (f & 31) * 4;
        *(float4*)&s_b[r][c4] = *(const float4*)(Wih + (size_t)(j0 + r) * 128 + c4);
    }
    __syncthreads();

    #pragma unroll
    for (int f = 0; f < 8; f++) {
        int idx = t + f * 256;
        int kk = idx >> 6, jj = idx & 63;
        float acc = 0.f;
        #pragma unroll 8
        for (int m = 0; m < 128; m++) acc += s_a[kk][m] * s_b[jj][m];
        Wbig[(size_t)(k0 + kk) * 512 + j0 + jj] = acc;
    }
    if (jt == 0) {
        for (int f = t; f < 32 * 128; f += 256) {
            int kk = f >> 7, jj = 384 + (f & 127);
            Wbig[(size_t)(k0 + kk) * 512 + jj] = 0.f;
        }
    }
}

// P0b: Wbig rows 128..255: j<256: Whh[j][kp]; 256..383: 0; j>=384: Whh[j-128][kp]
__global__ __launch_bounds__(256) void build_wbig_copy_kernel(
    const float* __restrict__ Whh, float* __restrict__ Wbig)
{
    int idx = blockIdx.x * 256 + threadIdx.x;   // 65536
    int kp = idx >> 9;
    int j = idx & 511;
    float v = 0.f;
    if (j < 256)       v = Whh[j * 128 + kp];
    else if (j >= 384) v = Whh[(j - 128) * 128 + kp];
    Wbig[(size_t)(128 + kp) * 512 + j] = v;
}

// P0c: bvec[c] = sum_m valb[m] * Wih[c][m],  c < 384
__global__ __launch_bounds__(256) void build_bvec_kernel(
    const float* __restrict__ valb, const float* __restrict__ Wih,
    float* __restrict__ bvec)
{
    int c = blockIdx.x * 256 + threadIdx.x;
    if (c < 384) {
        float acc = 0.f;
        #pragma unroll 8
        for (int m = 0; m < 128; m++) acc += valb[m] * Wih[c * 128 + m];
        bvec[c] = acc;
    }
}

// P0d: fp16 copy of nodes
__global__ __launch_bounds__(256) void nodes_to_half_kernel(
    const float* __restrict__ nodes, __half* __restrict__ nh)
{
    int i = blockIdx.x * 256 + threadIdx.x;   // one float4 (4 values) per thread
    if (i < N_NODES * D_NODE / 4) {
        float4 v = ((const float4*)nodes)[i];
        __half2 a = __floats2half2_rn(v.x, v.y);
        __half2 b = __floats2half2_rn(v.z, v.w);
        ((__half2*)nh)[i * 2]     = a;
        ((__half2*)nh)[i * 2 + 1] = b;
    }
}

// ---------------------------------------------------------------------------
// K1 v2: 32 particles/block. query = [ph|gr]@qW + qb; fold keyW/keyb.
// ---------------------------------------------------------------------------
__global__ __launch_bounds__(256) void query_qk_v2(
    const float* __restrict__ ph, const float* __restrict__ gr,
    const float* __restrict__ qW, const float* __restrict__ qb,
    const float* __restrict__ keyW, const float* __restrict__ keyb,
    float* __restrict__ qk, float* __restrict__ qoff)
{
    __shared__ float s_in[32][256];
    __shared__ float s_qW[256 * 20];
    __shared__ float s_kWT[20][128];
    __shared__ float s_q[32][20];

    int t = threadIdx.x;
    int pbase = blockIdx.x * 32;

    for (int f = t; f < 32 * 64; f += 256) {
        int pl = f >> 6, c4 = (f & 63) * 4;
        int p = min(pbase + pl, N_PART - 1);
        float4 v;
        if (c4 < 128) v = *(const float4*)(ph + (size_t)p * 128 + c4);
        else          v = *(const float4*)(gr + (size_t)p * 128 + (c4 - 128));
        *(float4*)&s_in[pl][c4] = v;
    }
    for (int f = t; f < 1280; f += 256)
        *(float4*)&s_qW[f * 4] = *(const float4*)(qW + f * 4);
    for (int f = t; f < 2560; f += 256) {
        int j = f / 20, a = f % 20;
        s_kWT[a][j] = keyW[f];
    }
    __syncthreads();

    for (int idx = t; idx < 32 * 20; idx += 256) {
        int pl = idx / 20, a = idx % 20;
        float acc = qb[a];
        #pragma unroll 8
        for (int k = 0; k < 256; k++) acc += s_in[pl][k] * s_qW[k * 20 + a];
        s_q[pl][a] = acc;
    }
    __syncthreads();

    for (int idx = t; idx < 32 * 128; idx += 256) {
        int pl = idx >> 7, j = idx & 127;
        int p = pbase + pl;
        if (p < N_PART) {
            float acc = 0.f;
            #pragma unroll
            for (int a = 0; a < D_ATT; a++) acc += s_kWT[a][j] * s_q[pl][a];
            qk[(size_t)p * 128 + j] = acc;
        }
    }
    if (t < 32) {
        int p = pbase + t;
        if (p < N_PART) {
            float o = 0.f;
            #pragma unroll
            for (int a = 0; a < D_ATT; a++) o += keyb[a] * s_q[t][a];
            qoff[p] = o;
        }
    }
}

// ---------------------------------------------------------------------------
// K2a: per-block LDS histogram of dst
// ---------------------------------------------------------------------------
__global__ __launch_bounds__(256) void block_hist_kernel(
    const int* __restrict__ dst, int* __restrict__ blockhist)
{
    __shared__ int h[N_PART];
    int b = blockIdx.x;
    for (int i = threadIdx.x; i < N_PART; i += 256) h[i] = 0;
    __syncthreads();
    int beg = b * EPB, end = min(beg + EPB, N_EDGES);
    for (int e = beg + threadIdx.x; e < end; e += 256)
        atomicAdd(&h[dst[e]], 1);
    __syncthreads();
    for (int i = threadIdx.x; i < N_PART; i += 256)
        blockhist[(size_t)b * N_PART + i] = h[i];
}

// K2b: per-dst column scan over blocks
__global__ __launch_bounds__(256) void colscan_kernel(
    int* __restrict__ blockhist, int* __restrict__ totals)
{
    int i = blockIdx.x * 256 + threadIdx.x;
    if (i >= N_PART) return;
    int run = 0;
    for (int b = 0; b < NBLK; b++) {
        size_t idx = (size_t)b * N_PART + i;
        int v = blockhist[idx];
        blockhist[idx] = run;
        run += v;
    }
    totals[i] = run;
}

// K2c: exclusive scan of totals[5000] -> offsets[5001]
__global__ __launch_bounds__(256) void scan_kernel(
    const int* __restrict__ totals, int* __restrict__ offsets)
{
    __shared__ int ss[256];
    int t = threadIdx.x;
    const int CH = 20;
    int beg = t * CH;
    int end = min(beg + CH, N_PART);
    int lsum = 0;
    for (int i = beg; i < end; i++) lsum += totals[i];
    ss[t] = lsum;
    __syncthreads();
    for (int off = 1; off < 256; off <<= 1) {
        int v = (t >= off) ? ss[t - off] : 0;
        __syncthreads();
        ss[t] += v;
        __syncthreads();
    }
    int base = ss[t] - lsum;
    for (int i = beg; i < end; i++) {
        offsets[i] = base;
        base += totals[i];
    }
    if (t == 0) offsets[N_PART] = N_EDGES;
}

// K2d: scatter src into dst-sorted order using per-block LDS cursors
__global__ __launch_bounds__(256) void scatter_sorted_kernel(
    const int* __restrict__ src, const int* __restrict__ dst,
    const int* __restrict__ offsets, const int* __restrict__ blockhist,
    int* __restrict__ ssrc)
{
    __shared__ int cur[N_PART];
    int b = blockIdx.x;
    for (int i = threadIdx.x; i < N_PART; i += 256)
        cur[i] = offsets[i] + blockhist[(size_t)b * N_PART + i];
    __syncthreads();
    int beg = b * EPB, end = min(beg + EPB, N_EDGES);
    for (int e = beg + threadIdx.x; e < end; e += 256) {
        int d = dst[e];
        int pos = atomicAdd(&cur[d], 1);
        ssrc[pos] = src[e];
    }
}

// ---------------------------------------------------------------------------
// K3 fp16: quarter-wave (16 lanes x 16B = 8 halves) per edge.
// 4 groups/wave x 4 waves: 16 edges concurrently per block, stride 32.
// ---------------------------------------------------------------------------
__global__ __launch_bounds__(256) void edge_agg_f16(
    const __half* __restrict__ nh, const float* __restrict__ qk,
    const float* __restrict__ qoff,
    const int* __restrict__ offsets, const int* __restrict__ ssrc,
    float* __restrict__ agg, float* __restrict__ att_sum)
{
    const float norm = 0.22360679774997896f;  // 1/sqrt(20)
    int p = blockIdx.x;
    int tid = threadIdx.x;
    int lane = tid & 63;
    int wave = tid >> 6;
    int lane16 = lane & 15;
    int col8 = lane16 * 8;

    float4 q0 = *(const float4*)(qk + (size_t)p * 128 + col8);
    float4 q1 = *(const float4*)(qk + (size_t)p * 128 + col8 + 4);
    float qo = qoff[p];
    int beg = offsets[p];
    int n = offsets[p + 1] - beg;

    float4 a0 = {0.f, 0.f, 0.f, 0.f};
    float4 a1 = {0.f, 0.f, 0.f, 0.f};
    float asum = 0.f;

    int i = wave * 8 + (lane >> 4);   // edge A; edge B = i+4; stride 32
    for (; i + 4 < n; i += 32) {
        int sA = ssrc[beg + i];
        int sB = ssrc[beg + i + 4];
        float4 rawA = *(const float4*)(nh + (size_t)sA * 128 + col8);
        float4 rawB = *(const float4*)(nh + (size_t)sB * 128 + col8);
        const __half2* hA = (const __half2*)&rawA;
        const __half2* hB = (const __half2*)&rawB;
        float2 xa0 = __half22float2(hA[0]), xa1 = __half22float2(hA[1]);
        float2 xa2 = __half22float2(hA[2]), xa3 = __half22float2(hA[3]);
        float2 xb0 = __half22float2(hB[0]), xb1 = __half22float2(hB[1]);
        float2 xb2 = __half22float2(hB[2]), xb3 = __half22float2(hB[3]);
        float dA = xa0.x * q0.x + xa0.y * q0.y + xa1.x * q0.z + xa1.y * q0.w
                 + xa2.x * q1.x + xa2.y * q1.y + xa3.x * q1.z + xa3.y * q1.w;
        float dB = xb0.x * q0.x + xb0.y * q0.y + xb1.x * q0.z + xb1.y * q0.w
                 + xb2.x * q1.x + xb2.y * q1.y + xb3.x * q1.z + xb3.y * q1.w;
        #pragma unroll
        for (int off = 1; off <= 8; off <<= 1) {
            dA += __shfl_xor(dA, off, 64);
            dB += __shfl_xor(dB, off, 64);
        }
        float attA = (dA + qo) * norm;
        float attB = (dB + qo) * norm;
        a0.x += attA * xa0.x + attB * xb0.x;
        a0.y += attA * xa0.y + attB * xb0.y;
        a0.z += attA * xa1.x + attB * xb1.x;
        a0.w += attA * xa1.y + attB * xb1.y;
        a1.x += attA * xa2.x + attB * xb2.x;
        a1.y += attA * xa2.y + attB * xb2.y;
        a1.z += attA * xa3.x + attB * xb3.x;
        a1.w += attA * xa3.y + attB * xb3.y;
        asum += attA + attB;
    }
    if (i < n) {
        int sA = ssrc[beg + i];
        float4 rawA = *(const float4*)(nh + (size_t)sA * 128 + col8);
        const __half2* hA = (const __half2*)&rawA;
        float2 xa0 = __half22float2(hA[0]), xa1 = __half22float2(hA[1]);
        float2 xa2 = __half22float2(hA[2]), xa3 = __half22float2(hA[3]);
        float dA = xa0.x * q0.x + xa0.y * q0.y + xa1.x * q0.z + xa1.y * q0.w
                 + xa2.x * q1.x + xa2.y * q1.y + xa3.x * q1.z + xa3.y * q1.w;
        #pragma unroll
        for (int off = 1; off <= 8; off <<= 1) dA += __shfl_xor(dA, off, 64);
        float attA = (dA + qo) * norm;
        a0.x += attA * xa0.x; a0.y += attA * xa0.y;
        a0.z += attA * xa1.x; a0.w += attA * xa1.y;
        a1.x += attA * xa2.x; a1.y += attA * xa2.y;
        a1.z += attA * xa3.x; a1.w += attA * xa3.y;
        asum += attA;
    }

    // cross-group reduce (xor 16, then 32)
    #pragma unroll
    for (int off = 16; off <= 32; off <<= 1) {
        a0.x += __shfl_xor(a0.x, off, 64);
        a0.y += __shfl_xor(a0.y, off, 64);
        a0.z += __shfl_xor(a0.z, off, 64);
        a0.w += __shfl_xor(a0.w, off, 64);
        a1.x += __shfl_xor(a1.x, off, 64);
        a1.y += __shfl_xor(a1.y, off, 64);
        a1.z += __shfl_xor(a1.z, off, 64);
        a1.w += __shfl_xor(a1.w, off, 64);
        asum += __shfl_xor(asum, off, 64);
    }

    __shared__ float s_part[4][128];
    __shared__ float s_as[4];
    if (lane < 16) {
        *(float4*)&s_part[wave][col8]     = a0;
        *(float4*)&s_part[wave][col8 + 4] = a1;
        if (lane == 0) s_as[wave] = asum;
    }
    __syncthreads();

    if (tid < 128) {
        float v = s_part[0][tid] + s_part[1][tid] + s_part[2][tid] + s_part[3][tid];
        agg[(size_t)p * 128 + tid] = v;
        if (tid == 0) att_sum[p] = s_as[0] + s_as[1] + s_as[2] + s_as[3];
    }
}

// ---------------------------------------------------------------------------
// K3 f32 fallback (R4 version): half-wave x float4, 4 pairs in flight.
// ---------------------------------------------------------------------------
__global__ __launch_bounds__(256) void edge_agg_f32(
    const float* __restrict__ nodes, const float* __restrict__ qk,
    const float* __restrict__ qoff,
    const int* __restrict__ offsets, const int* __restrict__ ssrc,
    float* __restrict__ agg, float* __restrict__ att_sum)
{
    const float norm = 0.22360679774997896f;
    int p = blockIdx.x;
    int tid = threadIdx.x;
    int lane = tid & 63;
    int wave = tid >> 6;
    int half = lane >> 5;
    int colq = (lane & 31) * 4;

    const float4 q = *(const float4*)(qk + (size_t)p * 128 + colq);
    float qo = qoff[p];
    int beg = offsets[p], end = offsets[p + 1];
    int n = end - beg;
    int np = (n + 1) >> 1;
    int npfull = n >> 1;

    float4 a = {0.f, 0.f, 0.f, 0.f};
    float asum = 0.f;

    int pi = wave;
    for (; pi + 12 < npfull; pi += 16) {
        int e0 = beg + 2 * pi + half;
        int s0 = ssrc[e0];
        int s1 = ssrc[e0 + 8];
        int s2 = ssrc[e0 + 16];
        int s3 = ssrc[e0 + 24];
        float4 x0 = *(const float4*)(nodes + (size_t)s0 * 128 + colq);
        float4 x1 = *(const float4*)(nodes + (size_t)s1 * 128 + colq);
        float4 x2 = *(const float4*)(nodes + (size_t)s2 * 128 + colq);
        float4 x3 = *(const float4*)(nodes + (size_t)s3 * 128 + colq);
        float d0 = x0.x * q.x + x0.y * q.y + x0.z * q.z + x0.w * q.w;
        float d1 = x1.x * q.x + x1.y * q.y + x1.z * q.z + x1.w * q.w;
        float d2 = x2.x * q.x + x2.y * q.y + x2.z * q.z + x2.w * q.w;
        float d3 = x3.x * q.x + x3.y * q.y + x3.z * q.z + x3.w * q.w;
        #pragma unroll
        for (int off = 1; off <= 16; off <<= 1) {
            d0 += __shfl_xor(d0, off, 64);
            d1 += __shfl_xor(d1, off, 64);
            d2 += __shfl_xor(d2, off, 64);
            d3 += __shfl_xor(d3, off, 64);
        }
        float t0 = (d0 + qo) * norm;
        float t1 = (d1 + qo) * norm;
        float t2 = (d2 + qo) * norm;
        float t3 = (d3 + qo) * norm;
        a.x += t0 * x0.x + t1 * x1.x + t2 * x2.x + t3 * x3.x;
        a.y += t0 * x0.y + t1 * x1.y + t2 * x2.y + t3 * x3.y;
        a.z += t0 * x0.z + t1 * x1.z + t2 * x2.z + t3 * x3.z;
        a.w += t0 * x0.w + t1 * x1.w + t2 * x2.w + t3 * x3.w;
        asum += t0 + t1 + t2 + t3;
    }
    for (; pi < np; pi += 4) {
        int e0 = beg + 2 * pi;
        bool has1 = (e0 + 1 < end);
        int s0 = ssrc[e0];
        int s1 = has1 ? ssrc[e0 + 1] : s0;
        int s = half ? s1 : s0;
        float4 x = *(const float4*)(nodes + (size_t)s * 128 + colq);
        float d = x.x * q.x + x.y * q.y + x.z * q.z + x.w * q.w;
        #pragma unroll
        for (int off = 1; off <= 16; off <<= 1) d += __shfl_xor(d, off, 64);
        float att = (d + qo) * norm;
        if (half && !has1) att = 0.f;
        a.x += att * x.x; a.y += att * x.y; a.z += att * x.z; a.w += att * x.w;
        asum += att;
    }

    a.x += __shfl_xor(a.x, 32, 64);
    a.y += __shfl_xor(a.y, 32, 64);
    a.z += __shfl_xor(a.z, 32, 64);
    a.w += __shfl_xor(a.w, 32, 64);
    asum += __shfl_xor(asum, 32, 64);

    __shared__ float s_acc[4][128];
    __shared__ float s_as[4];
    if (lane < 32) {
        *(float4*)&s_acc[wave][colq] = a;
        if (lane == 0) s_as[wave] = asum;
    }
    __syncthreads();

    if (tid < 128) {
        float v = s_acc[0][tid] + s_acc[1][tid] + s_acc[2][tid] + s_acc[3][tid];
        agg[(size_t)p * 128 + tid] = v;
        if (tid == 0) att_sum[p] = s_as[0] + s_as[1] + s_as[2] + s_as[3];
    }
}

// ---------------------------------------------------------------------------
// K4 v4: single K=256 GEMM G=[agg|h]@Wbig (+bias/asum*bvec) + gates+LN+MLP.
// ---------------------------------------------------------------------------
__global__ __launch_bounds__(256) void gru_fused_v4(
    const float* __restrict__ agg, const float* __restrict__ att_sum,
    const float* __restrict__ ph,
    const float* __restrict__ Wbig, const float* __restrict__ bvec,
    const float* __restrict__ bih, const float* __restrict__ bhh,
    const float* __restrict__ lng, const float* __restrict__ lnb,
    const float* __restrict__ W1, const float* __restrict__ b1,
    const float* __restrict__ W2, const float* __restrict__ b2,
    float* __restrict__ out)
{
    __shared__ float s_in[TPV3][256];
    __shared__ float s_acc[TPV3][512];
    __shared__ float s_ln[TPV3][128];
    __shared__ float s_hid[TPV3][64];

    int t = threadIdx.x;
    int pbase = blockIdx.x * TPV3;

    for (int f = t; f < TPV3 * 64; f += 256) {
        int pl = f >> 6, c4 = (f & 63) * 4;
        int p = pbase + pl;
        float4 v;
        if (c4 < 128) v = *(const float4*)(agg + (size_t)p * 128 + c4);
        else          v = *(const float4*)(ph + (size_t)p * 128 + (c4 - 128));
        *(float4*)&s_in[pl][c4] = v;
    }

    int jq = t & 127;
    int j4 = jq * 4;
    int pg = t >> 7;
    float4 cb, bv;
    if (j4 < 256) {
        float4 bi = *(const float4*)(bih + j4);
        float4 bh = *(const float4*)(bhh + j4);
        cb.x = bi.x + bh.x; cb.y = bi.y + bh.y; cb.z = bi.z + bh.z; cb.w = bi.w + bh.w;
        bv = *(const float4*)(bvec + j4);
    } else if (j4 < 384) {
        cb = *(const float4*)(bih + j4);
        bv = *(const float4*)(bvec + j4);
    } else {
        cb = *(const float4*)(bhh + (j4 - 128));
        bv.x = bv.y = bv.z = bv.w = 0.f;
    }
    float4 acc[5];
    #pragma unroll
    for (int i = 0; i < 5; i++) {
        float as = att_sum[pbase + pg * 5 + i];
        acc[i].x = cb.x + as * bv.x;
        acc[i].y = cb.y + as * bv.y;
        acc[i].z = cb.z + as * bv.z;
        acc[i].w = cb.w + as * bv.w;
    }
    __syncthreads();

    #pragma unroll 4
    for (int k = 0; k < 256; k++) {
        float4 w = *(const float4*)(Wbig + (size_t)k * 512 + j4);
        #pragma unroll
        for (int i = 0; i < 5; i++) {
            float x = s_in[pg * 5 + i][k];
            acc[i].x += x * w.x; acc[i].y += x * w.y;
            acc[i].z += x * w.z; acc[i].w += x * w.w;
        }
    }

    #pragma unroll
    for (int i = 0; i < 5; i++)
        *(float4*)&s_acc[pg * 5 + i][j4] = acc[i];
    __syncthreads();

    for (int idx = t; idx < TPV3 * 32; idx += 256) {
        int pl = idx >> 5, q = idx & 31;
        int c4 = q * 4;
        float4 r4 = *(const float4*)&s_acc[pl][c4];
        float4 z4 = *(const float4*)&s_acc[pl][128 + c4];
        float4 i4 = *(const float4*)&s_acc[pl][256 + c4];
        float4 n4 = *(const float4*)&s_acc[pl][384 + c4];
        float4 h4 = *(const float4*)&s_in[pl][128 + c4];
        float r0 = sigmoid_(r4.x), r1 = sigmoid_(r4.y), r2 = sigmoid_(r4.z), r3 = sigmoid_(r4.w);
        float z0 = sigmoid_(z4.x), z1 = sigmoid_(z4.y), z2 = sigmoid_(z4.z), z3 = sigmoid_(z4.w);
        float n0 = tanh_(i4.x + r0 * n4.x), n1 = tanh_(i4.y + r1 * n4.y);
        float n2 = tanh_(i4.z + r2 * n4.z), n3 = tanh_(i4.w + r3 * n4.w);
        float4 hn;
        hn.x = (1.f - z0) * n0 + z0 * h4.x;
        hn.y = (1.f - z1) * n1 + z1 * h4.y;
        hn.z = (1.f - z2) * n2 + z2 * h4.z;
        hn.w = (1.f - z3) * n3 + z3 * h4.w;
        *(float4*)&s_ln[pl][c4] = hn;
    }
    __syncthreads();

    {
        int wv = t >> 6, l = t & 63;
        for (int pl = wv; pl < TPV3; pl += 4) {
            float v0 = s_ln[pl][l * 2], v1 = s_ln[pl][l * 2 + 1];
            float sum = v0 + v1, sq = v0 * v0 + v1 * v1;
            #pragma unroll
            for (int off = 1; off <= 32; off <<= 1) {
                sum += __shfl_xor(sum, off, 64);
                sq  += __shfl_xor(sq, off, 64);
            }
            float mu = sum * (1.f / 128.f);
            float var = sq * (1.f / 128.f) - mu * mu;
            float rstd = rsqrtf(var + 1e-5f);
            s_ln[pl][l * 2]     = (v0 - mu) * rstd * lng[l * 2] + lnb[l * 2];
            s_ln[pl][l * 2 + 1] = (v1 - mu) * rstd * lng[l * 2 + 1] + lnb[l * 2 + 1];
        }
    }
    __syncthreads();

    for (int idx = t; idx < TPV3 * 64; idx += 256) {
        int pl = idx >> 6, u = idx & 63;
        float a0 = b1[u];
        #pragma unroll 4
        for (int k = 0; k < 128; k++) a0 += s_ln[pl][k] * W1[k * 64 + u];
        s_hid[pl][u] = fmaxf(a0, 0.f);
    }
    __syncthreads();

    for (int idx = t; idx < TPV3 * 32; idx += 256) {
        int pl = idx >> 5, q = idx & 31;
        int c4 = q * 4;
        float4 o = *(const float4*)(b2 + c4);
        #pragma unroll 4
        for (int u = 0; u < 64; u++) {
            float av = s_hid[pl][u];
            float4 w = *(const float4*)(W2 + u * 128 + c4);
            o.x += av * w.x; o.y += av * w.y; o.z += av * w.z; o.w += av * w.w;
        }
        float4 h4 = *(const float4*)&s_in[pl][128 + c4];
        float4 res;
        res.x = h4.x + o.x; res.y = h4.y + o.y;
        res.z = h4.z + o.z; res.w = h4.w + o.w;
        *(float4*)(out + (size_t)(pbase + pl) * 128 + c4) = res;
    }
}

// ---------------------------------------------------------------------------
extern "C" void kernel_launch(void* const* d_in, const int* in_sizes, int n_in,
                              void* d_out, int out_size, void* d_ws, size_t ws_size,
                              hipStream_t stream) {
    const float* nodes = (const float*)d_in[0];
    const float* ph    = (const float*)d_in[1];
    const float* gr    = (const float*)d_in[2];
    const int*   src   = (const int*)d_in[3];
    const int*   dst   = (const int*)d_in[4];
    const float* keyW  = (const float*)d_in[5];
    const float* keyb  = (const float*)d_in[6];
    const float* valW  = (const float*)d_in[7];
    const float* valb  = (const float*)d_in[8];
    const float* qW    = (const float*)d_in[9];
    const float* qb    = (const float*)d_in[10];
    const float* Wih   = (const float*)d_in[11];
    const float* Whh   = (const float*)d_in[12];
    const float* bih   = (const float*)d_in[13];
    const float* bhh   = (const float*)d_in[14];
    const float* lng   = (const float*)d_in[15];
    const float* lnb   = (const float*)d_in[16];
    const float* W1    = (const float*)d_in[17];
    const float* b1    = (const float*)d_in[18];
    const float* W2    = (const float*)d_in[19];
    const float* b2    = (const float*)d_in[20];
    float* out = (float*)d_out;

    // workspace layout (floats)
    float* ws_f      = (float*)d_ws;
    float* qk        = ws_f;                       // 640,000
    float* qoff      = qk + 640000;                // 5,008
    float* agg       = qoff + 5008;                // 640,000
    float* att_sum   = agg + 640000;               // 5,008
    float* Wbig      = att_sum + 5008;             // 131,072
    float* bvec      = Wbig + 131072;              // 512
    int*   totals    = (int*)(bvec + 512);         // 5,008
    int*   offsets   = totals + 5008;              // 5,008
    int*   blockhist = offsets + 5008;             // NBLK*5000 = 640,000
    int*   ssrc      = blockhist + (size_t)NBLK * N_PART;  // 1,000,000
    __half* nodes_h  = (__half*)(ssrc + 1000000);  // 12,800,000 halves

    size_t base_floats = 640000 + 5008 + 640000 + 5008 + 131072 + 512
                       + 5008 + 5008 + (size_t)NBLK * N_PART + 1000000;
    size_t need_f16 = base_floats * sizeof(float) + (size_t)N_NODES * D_NODE * sizeof(__half);
    bool use_f16 = (ws_size >= need_f16);

    build_wbig_dot_kernel<<<24, 256, 0, stream>>>(valW, Wih, Wbig);
    build_wbig_copy_kernel<<<256, 256, 0, stream>>>(Whh, Wbig);
    build_bvec_kernel<<<2, 256, 0, stream>>>(valb, Wih, bvec);
    query_qk_v2<<<(N_PART + 31) / 32, 256, 0, stream>>>(ph, gr, qW, qb, keyW, keyb, qk, qoff);
    block_hist_kernel<<<NBLK, 256, 0, stream>>>(dst, blockhist);
    colscan_kernel<<<(N_PART + 255) / 256, 256, 0, stream>>>(blockhist, totals);
    scan_kernel<<<1, 256, 0, stream>>>(totals, offsets);
    scatter_sorted_kernel<<<NBLK, 256, 0, stream>>>(src, dst, offsets, blockhist, ssrc);
    if (use_f16) {
        nodes_to_half_kernel<<<(N_NODES * D_NODE / 4 + 255) / 256, 256, 0, stream>>>(nodes, nodes_h);
        edge_agg_f16<<<N_PART, 256, 0, stream>>>(nodes_h, qk, qoff, offsets, ssrc, agg, att_sum);
    } else {
        edge_agg_f32<<<N_PART, 256, 0, stream>>>(nodes, qk, qoff, offsets, ssrc, agg, att_sum);
    }
    gru_fused_v4<<<N_PART / TPV3, 256, 0, stream>>>(
        agg, att_sum, ph, Wbig, bvec, bih, bhh, lng, lnb, W1, b1, W2, b2, out);
}